// Round 5
// baseline (273.633 us; speedup 1.0000x reference)
//
#include <hip/hip_runtime.h>
#include <math.h>
#include <float.h>

// VideoQuantizer: rmsnorm -> per-subvector argmin over 4096 codewords -> gather -> rmsnorm
// B=8 T=1024 D=1024 Q=8 K=4096 d=128
// v6: revert to v2 sync structure (2x16KB dbuf + __syncthreads; counted-vmcnt ring of v5
//     regressed). New: double-accumulator ping-pong — pack chunk c-1 (accB) interleaved
//     between chunk c's MFMA kt-groups (accA), breaking the MFMA->pack serialization that
//     pinned MfmaUtil=VALUBusy=44. c2 slab in LDS; no z-split; shortlist routing moved
//     into k_dist tail (k_merge + recs round-trip deleted). Shortlist rescue unchanged.
#define Q_     8
#define K_     4096
#define dd_    128
#define D_     1024
#define ROWS   8192
#define NCHUNK 64
#define TAU    0.02f   // rescue band on d2/2 scale (fp16-b err + 7-bit quant << 0.02)

typedef __attribute__((ext_vector_type(8))) _Float16 f16x8;
typedef __attribute__((ext_vector_type(4))) float f32x4;
typedef __attribute__((ext_vector_type(4))) unsigned int u32x4;

typedef const __attribute__((address_space(1))) unsigned int* gas_p;
typedef __attribute__((address_space(3))) unsigned int* las_p;

__device__ inline unsigned f2u(float x) { union { float f; unsigned u; } v; v.f = x; return v.u; }
__device__ inline float u2f(unsigned x) { union { unsigned u; float f; } v; v.u = x; return v.f; }
__device__ inline unsigned short f2h(float x) {
    union { _Float16 h; unsigned short u; } v; v.h = (_Float16)x; return v.u;
}
__device__ inline unsigned umin_(unsigned a, unsigned b) { return a < b ? a : b; }
__device__ inline unsigned umax_(unsigned a, unsigned b) { return a > b ? a : b; }
// order-preserving f32 -> u32 (total order; smaller float -> smaller uint)
__device__ inline unsigned fflip(float x) {
    unsigned u = f2u(x);
    return (u & 0x80000000u) ? ~u : (u | 0x80000000u);
}
__device__ inline unsigned long long shfl_xor_u64(unsigned long long v, int m) {
    unsigned lo = (unsigned)v, hi = (unsigned)(v >> 32);
    lo = __shfl_xor(lo, m, 64);
    hi = __shfl_xor(hi, m, 64);
    return ((unsigned long long)hi << 32) | lo;
}
// decode packed (tag|lane) -> codeword index; tag = (chunk<<1)|halfcol, e = lane index
__device__ inline unsigned dec_k(unsigned v, int e) {
    unsigned tg = v & 0x7Fu;
    return ((tg >> 1) << 6) | (((unsigned)e >> 4) << 5) | ((tg & 1u) << 4) | ((unsigned)e & 15u);
}

// ---------------- fused: panel build (negated fp16 plane) + c2/2 | input rmsnorm + x2/2 ----
// panels[q][c][n][slot][8 fp16] of NEGATED codewords; slot = j ^ (n&15)
__global__ void k_prep(const float* __restrict__ cb, const float* __restrict__ x,
                       const float* __restrict__ w, float* __restrict__ xn,
                       unsigned short* __restrict__ panels, float* __restrict__ c2h,
                       float* __restrict__ x2h, int* __restrict__ cntF, int* __restrict__ cntS) {
    const int bid = blockIdx.x, t = threadIdx.x;
    if (bid == 0 && t == 0) { *cntF = 0; *cntS = 0; }
    if (bid < NCHUNK * Q_) {
        // ---- panel prep ----
        int c = bid & 63, q = bid >> 6;
        const float* src = cb + ((size_t)q * K_ + c * 64) * dd_;
        unsigned short* dst = panels + (size_t)(q * NCHUNK + c) * 8192;
        #pragma unroll
        for (int i = 0; i < 4; i++) {
            int sid = i * 256 + t;
            int n = sid >> 4, j = sid & 15;
            const float* sp = src + n * dd_ + j * 8;
            f32x4 v0 = *(const f32x4*)sp;
            f32x4 v1 = *(const f32x4*)(sp + 4);
            float xs[8] = {v0.x, v0.y, v0.z, v0.w, v1.x, v1.y, v1.z, v1.w};
            unsigned short hb[8];
            float ss = 0.0f;
            #pragma unroll
            for (int e = 0; e < 8; e++) {
                float xv = -xs[e];                     // NEGATED codeword
                ss = fmaf(xv, xv, ss);
                hb[e] = f2h(xv);                       // single RTN fp16 plane
            }
            int slot = j ^ (n & 15);
            u32x4 H;
            H.x = (unsigned)hb[0] | ((unsigned)hb[1] << 16);
            H.y = (unsigned)hb[2] | ((unsigned)hb[3] << 16);
            H.z = (unsigned)hb[4] | ((unsigned)hb[5] << 16);
            H.w = (unsigned)hb[6] | ((unsigned)hb[7] << 16);
            *(u32x4*)&dst[(n * 16 + slot) * 8] = H;
            ss += __shfl_xor(ss, 1, 64);
            ss += __shfl_xor(ss, 2, 64);
            ss += __shfl_xor(ss, 4, 64);
            ss += __shfl_xor(ss, 8, 64);
            if (j == 0) c2h[q * K_ + c * 64 + n] = 0.5f * ss;   // exact f32 c2/2
        }
    } else {
        // ---- input rmsnorm + sub-vector x2/2 ----
        int row = bid - NCHUNK * Q_;
        const float4 v = *(const float4*)(x + (size_t)row * D_ + t * 4);
        float ss = v.x * v.x + v.y * v.y + v.z * v.z + v.w * v.w;
        #pragma unroll
        for (int o = 32; o > 0; o >>= 1) ss += __shfl_xor(ss, o, 64);
        __shared__ float acc[4];
        if ((t & 63) == 0) acc[t >> 6] = ss;
        __syncthreads();
        float tot = (acc[0] + acc[1]) + (acc[2] + acc[3]);
        float sc  = 1.0f / sqrtf(tot * (1.0f / D_) + 1e-5f);
        const float4 wv = *(const float4*)(w + t * 4);
        float4 o;
        o.x = v.x * sc * wv.x; o.y = v.y * sc * wv.y;
        o.z = v.z * sc * wv.z; o.w = v.w * sc * wv.w;
        *(float4*)(xn + (size_t)row * D_ + t * 4) = o;
        float so = o.x * o.x + o.y * o.y + o.z * o.z + o.w * o.w;
        so += __shfl_xor(so, 1, 64);
        so += __shfl_xor(so, 2, 64);
        so += __shfl_xor(so, 4, 64);
        so += __shfl_xor(so, 8, 64);
        so += __shfl_xor(so, 16, 64);
        if ((t & 31) == 0) x2h[row * Q_ + (t >> 5)] = 0.5f * so;
    }
}

// stage chunk CN's 16KB panel into its alternating 16KB LDS buffer
#define STAGE(CN) do {                                                                   \
    const char* src_ = (const char*)(panels + panq + (size_t)(CN) * 8192);               \
    char* stg_ = smem + ((CN) & 1) * 16384;                                              \
    _Pragma("unroll")                                                                    \
    for (int i_ = 0; i_ < 4; i_++) {                                                     \
        int boff_ = i_ * 4096 + t * 16;                                                  \
        __builtin_amdgcn_global_load_lds((gas_p)(src_ + boff_), (las_p)(stg_ + boff_),   \
                                         16, 0, 0);                                      \
    }                                                                                    \
} while (0)

// pack quarter MT of accumulator ACC (prev chunk's scores) into m1/m2
#define PACK_Q(ACC, MT, TG0, TG1, CH0, CH1) do {                                         \
    _Pragma("unroll")                                                                    \
    for (int r_ = 0; r_ < 4; r_++) {                                                     \
        const int sl_ = (MT) * 4 + r_;                                                   \
        unsigned p0_ = (f2u(ACC[MT][0][r_] + (CH0)) & 0xFFFFFF80u) | (TG0);              \
        unsigned p1_ = (f2u(ACC[MT][1][r_] + (CH1)) & 0xFFFFFF80u) | (TG1);              \
        unsigned pmin_ = umin_(p0_, p1_), pmax_ = umax_(p0_, p1_);                       \
        m2[sl_] = umin_(umin_(m2[sl_], umax_(m1[sl_], pmin_)), pmax_);                   \
        m1[sl_] = umin_(m1[sl_], pmin_);                                                 \
    }                                                                                    \
} while (0)

// one chunk phase: MFMAs of chunk C -> ACCW, pack of chunk C-1 from ACCP interleaved
#define PHASE(C, ACCW, ACCP) do {                                                        \
    __syncthreads();                                                                     \
    if ((C) + 1 < NCHUNK) STAGE((C) + 1);                                                \
    const char* cbuf_ = smem + ((C) & 1) * 16384;                                        \
    const int cp_ = (C) - 1;                                                             \
    const float pch0_ = c2s[cp_ * 64 + wn * 32 + col];                                   \
    const float pch1_ = c2s[cp_ * 64 + wn * 32 + col + 16];                              \
    const unsigned ptg0_ = ((unsigned)cp_ << 1) & 0x7Fu, ptg1_ = ptg0_ | 1u;             \
    _Pragma("unroll")                                                                    \
    for (int kt_ = 0; kt_ < 4; kt_++) {                                                  \
        const int sw_ = ((quad + kt_ * 4) ^ col) * 16;                                   \
        const int a0_ = (wn * 32 + col) * 256 + sw_;                                     \
        f16x8 b0_ = *(const f16x8*)(cbuf_ + a0_);                                        \
        f16x8 b1_ = *(const f16x8*)(cbuf_ + a0_ + 4096);                                 \
        _Pragma("unroll")                                                                \
        for (int mt_ = 0; mt_ < 4; mt_++) {                                              \
            f32x4 cin0_ = (kt_ == 0) ? x2v[mt_] : ACCW[mt_][0];                          \
            f32x4 cin1_ = (kt_ == 0) ? x2v[mt_] : ACCW[mt_][1];                          \
            ACCW[mt_][0] = __builtin_amdgcn_mfma_f32_16x16x32_f16(ah[mt_][kt_], b0_, cin0_, 0, 0, 0); \
            ACCW[mt_][0] = __builtin_amdgcn_mfma_f32_16x16x32_f16(al[mt_][kt_], b0_, ACCW[mt_][0], 0, 0, 0); \
            ACCW[mt_][1] = __builtin_amdgcn_mfma_f32_16x16x32_f16(ah[mt_][kt_], b1_, cin1_, 0, 0, 0); \
            ACCW[mt_][1] = __builtin_amdgcn_mfma_f32_16x16x32_f16(al[mt_][kt_], b1_, ACCW[mt_][1], 0, 0, 0); \
        }                                                                                \
        PACK_Q(ACCP, kt_, ptg0_, ptg1_, pch0_, pch1_);                                   \
    }                                                                                    \
} while (0)

// ---------------- 2-pass fp16 MFMA distance + double-acc interleaved top-2 pack ----------
// x split into fp16 hi+lo (~22 bits); B single fp16, negated. C-in = x2/2; c2/2 added at
// pack. acc_final = d2/2 >= 0; pack (score&~0x7F)|tag, u32 mins. Routing in tail:
// shortlist (<=5 rivals in band) or full-scan fallback (hidden-2nd in a lane / overflow).
__launch_bounds__(256, 2)
__global__ void k_dist(const float* __restrict__ xn, const unsigned short* __restrict__ panels,
                       const float* __restrict__ c2h, const float* __restrict__ x2h,
                       int* __restrict__ idxi, float* __restrict__ idxf,
                       int* __restrict__ listF, int* __restrict__ cntF,
                       int* __restrict__ srl, int* __restrict__ cntS,
                       unsigned long long* __restrict__ resc) {
    __shared__ char smem[49152];   // 2x16KB staging | 16KB c2 slab; reduce scratch overlaid

    const int t    = threadIdx.x;
    const int lane = t & 63, wave = t >> 6;
    const int wm = wave >> 1, wn = wave & 1;
    const int col = lane & 15, quad = lane >> 4;
    const int q = blockIdx.y;
    const int row0 = blockIdx.x * 128;

    // A fragments (fp16 round-to-nearest split: x ~= hi + lo to ~22 bits)
    f16x8 ah[4][4], al[4][4];
    #pragma unroll
    for (int mt = 0; mt < 4; mt++) {
        #pragma unroll
        for (int kt = 0; kt < 4; kt++) {
            const float* ap = xn + (size_t)(row0 + wm * 64 + mt * 16 + col) * D_
                              + q * dd_ + kt * 32 + quad * 8;
            f32x4 v0 = *(const f32x4*)ap;
            f32x4 v1 = *(const f32x4*)(ap + 4);
            #pragma unroll
            for (int e = 0; e < 8; e++) {
                float xv = (e < 4) ? v0[e] : v1[e - 4];
                _Float16 h = (_Float16)xv;
                float r = xv - (float)h;
                ah[mt][kt][e] = h;
                al[mt][kt][e] = (_Float16)r;
            }
        }
    }

    // per-slot row halves of ||x_q||^2 (MFMA C-in)
    f32x4 x2v[4];
    #pragma unroll
    for (int mt = 0; mt < 4; mt++)
        #pragma unroll
        for (int r = 0; r < 4; r++)
            x2v[mt][r] = x2h[(size_t)(row0 + wm * 64 + mt * 16 + quad * 4 + r) * Q_ + q];

    unsigned m1[16], m2[16];
    #pragma unroll
    for (int i = 0; i < 16; i++) { m1[i] = 0xFFFFFFFFu; m2[i] = 0xFFFFFFFFu; }

    const size_t panq = (size_t)q * NCHUNK * 8192;
    const float* c2s = (const float*)(smem + 32768);

    // prologue: stage c2 slab (16KB) + chunk 0
    {
        const char* c2src = (const char*)(c2h + (size_t)q * K_);
        #pragma unroll
        for (int i = 0; i < 4; i++) {
            int boff = i * 4096 + t * 16;
            __builtin_amdgcn_global_load_lds((gas_p)(c2src + boff),
                                             (las_p)(smem + 32768 + boff), 16, 0, 0);
        }
        STAGE(0);
    }

    f32x4 accA[4][2], accB[4][2];
    const f32x4 big = {1e30f, 1e30f, 1e30f, 1e30f};   // first pack of accB is a no-op
    #pragma unroll
    for (int mt = 0; mt < 4; mt++) { accB[mt][0] = big; accB[mt][1] = big; }

    for (int cc = 0; cc < NCHUNK; cc += 2) {
        PHASE(cc,     accA, accB);   // MFMA chunk cc   -> accA | pack chunk cc-1 (accB)
        PHASE(cc + 1, accB, accA);   // MFMA chunk cc+1 -> accB | pack chunk cc   (accA)
    }
    {   // tail: pack chunk 63 (accB)
        const float pch0_ = c2s[63 * 64 + wn * 32 + col];
        const float pch1_ = c2s[63 * 64 + wn * 32 + col + 16];
        const unsigned ptg0_ = (unsigned)(63 << 1), ptg1_ = ptg0_ | 1u;
        PACK_Q(accB, 0, ptg0_, ptg1_, pch0_, pch1_);
        PACK_Q(accB, 1, ptg0_, ptg1_, pch0_, pch1_);
        PACK_Q(accB, 2, ptg0_, ptg1_, pch0_, pch1_);
        PACK_Q(accB, 3, ptg0_, ptg1_, pch0_, pch1_);
    }

    // cross-lane merge per row (u32 domain; stride 33): min + shortlist + fallback detect
    __syncthreads();
    unsigned* rm1 = (unsigned*)smem;             // [128][33]
    unsigned* rm2 = (unsigned*)(smem + 16896);
    #pragma unroll
    for (int mt = 0; mt < 4; mt++) {
        #pragma unroll
        for (int r = 0; r < 4; r++) {
            int sl = mt * 4 + r;
            int row_l = wm * 64 + mt * 16 + quad * 4 + r;
            int e = wn * 16 + col;
            rm1[row_l * 33 + e] = m1[sl];
            rm2[row_l * 33 + e] = m2[sl];
        }
    }
    __syncthreads();
    if (t < 128) {
        unsigned b1 = 0xFFFFFFFFu;
        int be = 0;
        for (int e = 0; e < 32; e++) {
            unsigned v1 = rm1[t * 33 + e];
            if (v1 < b1) { b1 = v1; be = e; }
        }
        float thr = u2f(b1 & 0xFFFFFF80u) + TAU;
        int ns = 0, fb = 0;
        unsigned long long candpack = 0;
        for (int e = 0; e < 32; e++) {
            if (u2f(rm2[t * 33 + e] & 0xFFFFFF80u) < thr) fb = 1;   // hidden 2nd-in-lane
            if (e != be) {
                unsigned v1 = rm1[t * 33 + e];
                if (u2f(v1 & 0xFFFFFF80u) < thr) {
                    if (ns < 5) candpack |= (unsigned long long)dec_k(v1, e) << (12 * ns);
                    ns++;
                }
            }
        }
        if (ns > 5) fb = 1;
        unsigned k1 = dec_k(b1, be);
        int item = (row0 + t) * Q_ + q;
        idxi[item] = (int)k1;
        idxf[item] = (float)k1;
        if (fb) {
            resc[item] = 0xFFFFFFFFFFFFFFFFull;
            int p = atomicAdd(cntF, 1);
            listF[p] = item;
        } else if (ns > 0) {
            int p = atomicAdd(cntS, 1);
            int* e8 = srl + (size_t)p * 8;
            e8[0] = item; e8[1] = ns + 1; e8[2] = (int)k1;
            for (int i = 0; i < ns; i++)
                e8[3 + i] = (int)((candpack >> (12 * i)) & 0xFFFu);
        }
    }
}

// ---------------- exact fp32 rescue: shortlist blocks (<=6 cand) + full-scan fallback ----
__global__ void k_rescue(const float* __restrict__ xn, const float* __restrict__ cb,
                         const float* __restrict__ c2h, const int* __restrict__ listF,
                         const int* __restrict__ cntF, const int* __restrict__ srl,
                         const int* __restrict__ cntS,
                         unsigned long long* __restrict__ resc,
                         int* __restrict__ idxi, float* __restrict__ idxf) {
    __shared__ float xq[dd_];
    __shared__ unsigned long long kshare[8];
    const int t = threadIdx.x;
    if (blockIdx.x < 2048) {
        // ---- full-scan fallback: 8 blocks/item x 512 codewords ----
        const int n = *cntF;
        const int seg = blockIdx.x & 7;
        for (int ii = blockIdx.x >> 3; ii < n; ii += 256) {
            __syncthreads();
            int item = listF[ii];
            int rg = item >> 3, q = item & 7;
            if (t < dd_) xq[t] = xn[(size_t)rg * D_ + q * dd_ + t];
            __syncthreads();
            unsigned long long best = 0xFFFFFFFFFFFFFFFFull;
            #pragma unroll
            for (int i = 0; i < 2; i++) {
                int k = seg * 512 + i * 256 + t;
                const float* cp = cb + ((size_t)q * K_ + k) * dd_;
                float dot = 0.0f;
                #pragma unroll 8
                for (int d = 0; d < dd_; d += 4) {
                    f32x4 cv = *(const f32x4*)(cp + d);
                    dot = fmaf(cv.x, xq[d],     dot);
                    dot = fmaf(cv.y, xq[d + 1], dot);
                    dot = fmaf(cv.z, xq[d + 2], dot);
                    dot = fmaf(cv.w, xq[d + 3], dot);
                }
                float s = c2h[q * K_ + k] - dot;   // d2/2 - x2/2 (monotone in d2)
                unsigned long long key = ((unsigned long long)fflip(s) << 32) | (unsigned)k;
                best = best < key ? best : key;
            }
            #pragma unroll
            for (int o = 32; o > 0; o >>= 1) {
                unsigned long long other = shfl_xor_u64(best, o);
                best = best < other ? best : other;
            }
            if ((t & 63) == 0) kshare[t >> 6] = best;
            __syncthreads();
            if (t == 0) {
                unsigned long long b = kshare[0];
                b = b < kshare[1] ? b : kshare[1];
                b = b < kshare[2] ? b : kshare[2];
                b = b < kshare[3] ? b : kshare[3];
                atomicMin(&resc[item], b);
            }
        }
    } else {
        // ---- shortlist: 1 block/item, candidate per 32-lane group ----
        const int n = *cntS;
        for (int ii = (int)blockIdx.x - 2048; ii < n; ii += 2048) {
            __syncthreads();
            const int* e = srl + (size_t)ii * 8;
            int item = e[0], nc = e[1];
            int rg = item >> 3, q = item & 7;
            if (t < dd_) xq[t] = xn[(size_t)rg * D_ + q * dd_ + t];
            __syncthreads();
            int g = t >> 5, l = t & 31;
            unsigned long long key = 0xFFFFFFFFFFFFFFFFull;
            if (g < nc) {
                int k = e[2 + g];
                const float* cp = cb + ((size_t)q * K_ + k) * dd_ + l * 4;
                f32x4 cv = *(const f32x4*)cp;
                float dot = cv.x * xq[l * 4]     + cv.y * xq[l * 4 + 1]
                          + cv.z * xq[l * 4 + 2] + cv.w * xq[l * 4 + 3];
                dot += __shfl_xor(dot, 16, 64);
                dot += __shfl_xor(dot, 8, 64);
                dot += __shfl_xor(dot, 4, 64);
                dot += __shfl_xor(dot, 2, 64);
                dot += __shfl_xor(dot, 1, 64);
                float s = c2h[q * K_ + k] - dot;
                key = ((unsigned long long)fflip(s) << 32) | (unsigned)k;
            }
            if (l == 0) kshare[g] = key;
            __syncthreads();
            if (t == 0) {
                unsigned long long b = kshare[0];
                #pragma unroll
                for (int gg = 1; gg < 8; gg++) b = b < kshare[gg] ? b : kshare[gg];
                int k = (int)(unsigned)(b & 0xFFFFFFFFull);
                idxi[item] = k;
                idxf[item] = (float)k;
            }
        }
    }
}

// ---------------- decode full-scan winners into idxi/idxf ----------------
__global__ void k_fin(const int* __restrict__ listF, const int* __restrict__ cntF,
                      const unsigned long long* __restrict__ resc,
                      int* __restrict__ idxi, float* __restrict__ idxf) {
    const int n = *cntF;
    for (int i = blockIdx.x * blockDim.x + threadIdx.x; i < n; i += gridDim.x * blockDim.x) {
        int item = listF[i];
        int k = (int)(unsigned)(resc[item] & 0xFFFFFFFFull);
        idxi[item] = k;
        idxf[item] = (float)k;
    }
}

// ---------------- gather + output rmsnorm ----------------
__global__ void k_out(const float* __restrict__ cb, const int* __restrict__ idx_i,
                      const float* __restrict__ w, float* __restrict__ out) {
    int row = blockIdx.x;
    int t   = threadIdx.x;
    __shared__ int   sidx[Q_];
    __shared__ float acc[4];
    if (t < Q_) sidx[t] = idx_i[row * Q_ + t];
    __syncthreads();
    int col = t * 4;
    int q   = col >> 7;
    int dc  = col & 127;
    const float4 v = *(const float4*)(cb + ((size_t)q * K_ + sidx[q]) * dd_ + dc);
    float ss = v.x * v.x + v.y * v.y + v.z * v.z + v.w * v.w;
    #pragma unroll
    for (int o = 32; o > 0; o >>= 1) ss += __shfl_xor(ss, o, 64);
    if ((t & 63) == 0) acc[t >> 6] = ss;
    __syncthreads();
    float tot = (acc[0] + acc[1]) + (acc[2] + acc[3]);
    float sc  = 1.0f / sqrtf(tot * (1.0f / D_) + 1e-5f);
    const float4 wv = *(const float4*)(w + col);
    float4 o;
    o.x = v.x * sc * wv.x; o.y = v.y * sc * wv.y;
    o.z = v.z * sc * wv.z; o.w = v.w * sc * wv.w;
    *(float4*)(out + (size_t)row * D_ + col) = o;
}

extern "C" void kernel_launch(void* const* d_in, const int* in_sizes, int n_in,
                              void* d_out, int out_size, void* d_ws, size_t ws_size,
                              hipStream_t stream) {
    const float* x     = (const float*)d_in[0];
    const float* cb    = (const float*)d_in[1];
    const float* w_in  = (const float*)d_in[2];
    const float* w_out = (const float*)d_in[3];

    float* out  = (float*)d_out;                  // xn lives here between k_prep and k_out
    float* idxf = out + (size_t)ROWS * D_;

    // ws: panels 8MB | c2h 128KB | x2h 256KB | resc 512KB | idxi 256KB | listF 256KB
    //   | srl 2MB | cntF,cntS
    unsigned short* panels = (unsigned short*)d_ws;
    float* c2h  = (float*)((char*)d_ws + (8u << 20));
    float* x2h  = c2h + Q_ * K_;
    unsigned long long* resc = (unsigned long long*)(x2h + (size_t)ROWS * Q_);
    int*   idxi = (int*)(resc + (size_t)ROWS * Q_);
    int*   listF = idxi + ROWS * Q_;
    int*   srl  = listF + ROWS * Q_;
    int*   cntF = srl + (size_t)ROWS * Q_ * 8;
    int*   cntS = cntF + 1;

    k_prep  <<<dim3(NCHUNK * Q_ + ROWS), 256, 0, stream>>>(cb, x, w_in, out, panels, c2h, x2h, cntF, cntS);
    k_dist  <<<dim3(ROWS / 128, Q_),     256, 0, stream>>>(out, panels, c2h, x2h, idxi, idxf, listF, cntF, srl, cntS, resc);
    k_rescue<<<dim3(4096),               256, 0, stream>>>(out, cb, c2h, listF, cntF, srl, cntS, resc, idxi, idxf);
    k_fin   <<<dim3(64),                 256, 0, stream>>>(listF, cntF, resc, idxi, idxf);
    k_out   <<<dim3(ROWS),               256, 0, stream>>>(cb, idxi, w_out, out);
}

// Round 6
// 249.104 us; speedup vs baseline: 1.0985x; 1.0985x over previous
//
#include <hip/hip_runtime.h>
#include <math.h>
#include <float.h>

// VideoQuantizer: rmsnorm -> per-subvector argmin over 4096 codewords -> gather -> rmsnorm
// B=8 T=1024 D=1024 Q=8 K=4096 d=128
// v7: occupancy play. v2's proven 2-barrier loop (v5 ring / v6 interleave both regressed).
//     64-row blocks (grid 128x8), 2 mt per wave -> A-fragments 128->64 VGPR, total ~120;
//     __launch_bounds__(256,4) pins <=128 -> 4 waves/SIMD, 4 blocks/CU (LDS 32KB).
//     Tail routing (shortlist/fallback) kept in k_dist; rescue kernels unchanged.
#define Q_     8
#define K_     4096
#define dd_    128
#define D_     1024
#define ROWS   8192
#define NCHUNK 64
#define TAU    0.02f   // rescue band on d2/2 scale (fp16-b err + 7-bit quant << 0.02)

typedef __attribute__((ext_vector_type(8))) _Float16 f16x8;
typedef __attribute__((ext_vector_type(4))) float f32x4;
typedef __attribute__((ext_vector_type(4))) unsigned int u32x4;

typedef const __attribute__((address_space(1))) unsigned int* gas_p;
typedef __attribute__((address_space(3))) unsigned int* las_p;

__device__ inline unsigned f2u(float x) { union { float f; unsigned u; } v; v.f = x; return v.u; }
__device__ inline float u2f(unsigned x) { union { unsigned u; float f; } v; v.u = x; return v.f; }
__device__ inline unsigned short f2h(float x) {
    union { _Float16 h; unsigned short u; } v; v.h = (_Float16)x; return v.u;
}
__device__ inline unsigned umin_(unsigned a, unsigned b) { return a < b ? a : b; }
__device__ inline unsigned umax_(unsigned a, unsigned b) { return a > b ? a : b; }
// order-preserving f32 -> u32 (total order; smaller float -> smaller uint)
__device__ inline unsigned fflip(float x) {
    unsigned u = f2u(x);
    return (u & 0x80000000u) ? ~u : (u | 0x80000000u);
}
__device__ inline unsigned long long shfl_xor_u64(unsigned long long v, int m) {
    unsigned lo = (unsigned)v, hi = (unsigned)(v >> 32);
    lo = __shfl_xor(lo, m, 64);
    hi = __shfl_xor(hi, m, 64);
    return ((unsigned long long)hi << 32) | lo;
}
// decode packed (tag|lane) -> codeword index; tag = (chunk<<1)|halfcol, e = lane index
__device__ inline unsigned dec_k(unsigned v, int e) {
    unsigned tg = v & 0x7Fu;
    return ((tg >> 1) << 6) | (((unsigned)e >> 4) << 5) | ((tg & 1u) << 4) | ((unsigned)e & 15u);
}

// ---------------- fused: panel build (negated fp16 plane) + c2/2 | input rmsnorm + x2/2 ----
// panels[q][c][n][slot][8 fp16] of NEGATED codewords; slot = j ^ (n&15)
__global__ void k_prep(const float* __restrict__ cb, const float* __restrict__ x,
                       const float* __restrict__ w, float* __restrict__ xn,
                       unsigned short* __restrict__ panels, float* __restrict__ c2h,
                       float* __restrict__ x2h, int* __restrict__ cntF, int* __restrict__ cntS) {
    const int bid = blockIdx.x, t = threadIdx.x;
    if (bid == 0 && t == 0) { *cntF = 0; *cntS = 0; }
    if (bid < NCHUNK * Q_) {
        // ---- panel prep ----
        int c = bid & 63, q = bid >> 6;
        const float* src = cb + ((size_t)q * K_ + c * 64) * dd_;
        unsigned short* dst = panels + (size_t)(q * NCHUNK + c) * 8192;
        #pragma unroll
        for (int i = 0; i < 4; i++) {
            int sid = i * 256 + t;
            int n = sid >> 4, j = sid & 15;
            const float* sp = src + n * dd_ + j * 8;
            f32x4 v0 = *(const f32x4*)sp;
            f32x4 v1 = *(const f32x4*)(sp + 4);
            float xs[8] = {v0.x, v0.y, v0.z, v0.w, v1.x, v1.y, v1.z, v1.w};
            unsigned short hb[8];
            float ss = 0.0f;
            #pragma unroll
            for (int e = 0; e < 8; e++) {
                float xv = -xs[e];                     // NEGATED codeword
                ss = fmaf(xv, xv, ss);
                hb[e] = f2h(xv);                       // single RTN fp16 plane
            }
            int slot = j ^ (n & 15);
            u32x4 H;
            H.x = (unsigned)hb[0] | ((unsigned)hb[1] << 16);
            H.y = (unsigned)hb[2] | ((unsigned)hb[3] << 16);
            H.z = (unsigned)hb[4] | ((unsigned)hb[5] << 16);
            H.w = (unsigned)hb[6] | ((unsigned)hb[7] << 16);
            *(u32x4*)&dst[(n * 16 + slot) * 8] = H;
            ss += __shfl_xor(ss, 1, 64);
            ss += __shfl_xor(ss, 2, 64);
            ss += __shfl_xor(ss, 4, 64);
            ss += __shfl_xor(ss, 8, 64);
            if (j == 0) c2h[q * K_ + c * 64 + n] = 0.5f * ss;   // exact f32 c2/2
        }
    } else {
        // ---- input rmsnorm + sub-vector x2/2 ----
        int row = bid - NCHUNK * Q_;
        const float4 v = *(const float4*)(x + (size_t)row * D_ + t * 4);
        float ss = v.x * v.x + v.y * v.y + v.z * v.z + v.w * v.w;
        #pragma unroll
        for (int o = 32; o > 0; o >>= 1) ss += __shfl_xor(ss, o, 64);
        __shared__ float acc[4];
        if ((t & 63) == 0) acc[t >> 6] = ss;
        __syncthreads();
        float tot = (acc[0] + acc[1]) + (acc[2] + acc[3]);
        float sc  = 1.0f / sqrtf(tot * (1.0f / D_) + 1e-5f);
        const float4 wv = *(const float4*)(w + t * 4);
        float4 o;
        o.x = v.x * sc * wv.x; o.y = v.y * sc * wv.y;
        o.z = v.z * sc * wv.z; o.w = v.w * sc * wv.w;
        *(float4*)(xn + (size_t)row * D_ + t * 4) = o;
        float so = o.x * o.x + o.y * o.y + o.z * o.z + o.w * o.w;
        so += __shfl_xor(so, 1, 64);
        so += __shfl_xor(so, 2, 64);
        so += __shfl_xor(so, 4, 64);
        so += __shfl_xor(so, 8, 64);
        so += __shfl_xor(so, 16, 64);
        if ((t & 31) == 0) x2h[row * Q_ + (t >> 5)] = 0.5f * so;
    }
}

// stage chunk CN's 16KB panel into its alternating 16KB LDS buffer
#define STAGE(CN) do {                                                                   \
    const char* src_ = (const char*)(panels + panq + (size_t)(CN) * 8192);               \
    char* stg_ = smem + ((CN) & 1) * 16384;                                              \
    _Pragma("unroll")                                                                    \
    for (int i_ = 0; i_ < 4; i_++) {                                                     \
        int boff_ = i_ * 4096 + t * 16;                                                  \
        __builtin_amdgcn_global_load_lds((gas_p)(src_ + boff_), (las_p)(stg_ + boff_),   \
                                         16, 0, 0);                                      \
    }                                                                                    \
} while (0)

// ---------------- 2-pass fp16 MFMA distance (64-row blocks) + packed-u32 top-2 ----------
// x split into fp16 hi+lo (~22 bits); B single fp16, negated. acc init = x2/2 + c2/2
// -> acc_final = d2/2 >= 0; pack (score&~0x7F)|tag, u32 mins. Routing in tail:
// shortlist (<=5 rivals in band) or full-scan fallback (hidden-2nd in a lane / overflow).
__launch_bounds__(256, 4)
__global__ void k_dist(const float* __restrict__ xn, const unsigned short* __restrict__ panels,
                       const float* __restrict__ c2h, const float* __restrict__ x2h,
                       int* __restrict__ idxi, float* __restrict__ idxf,
                       int* __restrict__ listF, int* __restrict__ cntF,
                       int* __restrict__ srl, int* __restrict__ cntS,
                       unsigned long long* __restrict__ resc) {
    __shared__ char smem[32768];   // 2 x 16KB staging; reduce scratch (16896B) overlaid

    const int t    = threadIdx.x;
    const int lane = t & 63, wave = t >> 6;
    const int wm = wave >> 1, wn = wave & 1;
    const int col = lane & 15, quad = lane >> 4;
    const int q = blockIdx.y;
    const int row0 = blockIdx.x * 64;

    // A fragments (fp16 round-to-nearest split: x ~= hi + lo to ~22 bits), 2 mt per wave
    f16x8 ah[2][4], al[2][4];
    #pragma unroll
    for (int mt = 0; mt < 2; mt++) {
        #pragma unroll
        for (int kt = 0; kt < 4; kt++) {
            const float* ap = xn + (size_t)(row0 + wm * 32 + mt * 16 + col) * D_
                              + q * dd_ + kt * 32 + quad * 8;
            f32x4 v0 = *(const f32x4*)ap;
            f32x4 v1 = *(const f32x4*)(ap + 4);
            #pragma unroll
            for (int e = 0; e < 8; e++) {
                float xv = (e < 4) ? v0[e] : v1[e - 4];
                _Float16 h = (_Float16)xv;
                float r = xv - (float)h;
                ah[mt][kt][e] = h;
                al[mt][kt][e] = (_Float16)r;
            }
        }
    }

    // per-slot row halves of ||x_q||^2
    f32x4 x2v[2];
    #pragma unroll
    for (int mt = 0; mt < 2; mt++)
        #pragma unroll
        for (int r = 0; r < 4; r++)
            x2v[mt][r] = x2h[(size_t)(row0 + wm * 32 + mt * 16 + quad * 4 + r) * Q_ + q];

    unsigned m1[8], m2[8];
    #pragma unroll
    for (int i = 0; i < 8; i++) { m1[i] = 0xFFFFFFFFu; m2[i] = 0xFFFFFFFFu; }

    const size_t panq = (size_t)q * NCHUNK * 8192;
    const float* c2hq = c2h + q * K_;

    STAGE(0);
    float ch0 = c2hq[wn * 32 + col];
    float ch1 = c2hq[wn * 32 + col + 16];

    for (int c = 0; c < NCHUNK; c++) {
        __syncthreads();
        if (c + 1 < NCHUNK) STAGE(c + 1);
        float ch0n = 0.0f, ch1n = 0.0f;
        if (c + 1 < NCHUNK) {
            ch0n = c2hq[(c + 1) * 64 + wn * 32 + col];
            ch1n = c2hq[(c + 1) * 64 + wn * 32 + col + 16];
        }
        const char* cbuf = smem + (c & 1) * 16384;

        f32x4 acc[2][2];
        #pragma unroll
        for (int mt = 0; mt < 2; mt++) {
            acc[mt][0] = x2v[mt] + ch0;   // d2/2 accumulator init
            acc[mt][1] = x2v[mt] + ch1;
        }

        #pragma unroll
        for (int kt = 0; kt < 4; kt++) {
            const int sw = ((quad + kt * 4) ^ col) * 16;
            const int a0 = (wn * 32 + col) * 256 + sw;        // codeword rows 0..15 of half 0
            const int a1 = a0 + 4096;                         // +16 rows (half 1)
            f16x8 b0 = *(const f16x8*)(cbuf + a0);
            f16x8 b1 = *(const f16x8*)(cbuf + a1);
            #pragma unroll
            for (int mt = 0; mt < 2; mt++) {
                acc[mt][0] = __builtin_amdgcn_mfma_f32_16x16x32_f16(ah[mt][kt], b0, acc[mt][0], 0, 0, 0);
                acc[mt][0] = __builtin_amdgcn_mfma_f32_16x16x32_f16(al[mt][kt], b0, acc[mt][0], 0, 0, 0);
                acc[mt][1] = __builtin_amdgcn_mfma_f32_16x16x32_f16(ah[mt][kt], b1, acc[mt][1], 0, 0, 0);
                acc[mt][1] = __builtin_amdgcn_mfma_f32_16x16x32_f16(al[mt][kt], b1, acc[mt][1], 0, 0, 0);
            }
        }

        const unsigned tg0 = (unsigned)(c << 1), tg1 = tg0 | 1u;
        #pragma unroll
        for (int mt = 0; mt < 2; mt++) {
            #pragma unroll
            for (int r = 0; r < 4; r++) {
                const int sl = mt * 4 + r;
                unsigned p0 = (f2u(acc[mt][0][r]) & 0xFFFFFF80u) | tg0;
                unsigned p1 = (f2u(acc[mt][1][r]) & 0xFFFFFF80u) | tg1;
                unsigned pmin = umin_(p0, p1), pmax = umax_(p0, p1);
                m2[sl] = umin_(umin_(m2[sl], umax_(m1[sl], pmin)), pmax);  // min3 fusion
                m1[sl] = umin_(m1[sl], pmin);
            }
        }
        ch0 = ch0n; ch1 = ch1n;
    }

    // cross-lane merge per row (u32 domain; stride 33): min + shortlist + fallback detect
    __syncthreads();
    unsigned* rm1 = (unsigned*)smem;             // [64][33]
    unsigned* rm2 = (unsigned*)(smem + 8448);
    #pragma unroll
    for (int mt = 0; mt < 2; mt++) {
        #pragma unroll
        for (int r = 0; r < 4; r++) {
            int sl = mt * 4 + r;
            int row_l = wm * 32 + mt * 16 + quad * 4 + r;
            int e = wn * 16 + col;
            rm1[row_l * 33 + e] = m1[sl];
            rm2[row_l * 33 + e] = m2[sl];
        }
    }
    __syncthreads();
    if (t < 64) {
        unsigned b1 = 0xFFFFFFFFu;
        int be = 0;
        for (int e = 0; e < 32; e++) {
            unsigned v1 = rm1[t * 33 + e];
            if (v1 < b1) { b1 = v1; be = e; }
        }
        float thr = u2f(b1 & 0xFFFFFF80u) + TAU;
        int ns = 0, fb = 0;
        unsigned long long candpack = 0;
        for (int e = 0; e < 32; e++) {
            if (u2f(rm2[t * 33 + e] & 0xFFFFFF80u) < thr) fb = 1;   // hidden 2nd-in-lane
            if (e != be) {
                unsigned v1 = rm1[t * 33 + e];
                if (u2f(v1 & 0xFFFFFF80u) < thr) {
                    if (ns < 5) candpack |= (unsigned long long)dec_k(v1, e) << (12 * ns);
                    ns++;
                }
            }
        }
        if (ns > 5) fb = 1;
        unsigned k1 = dec_k(b1, be);
        int item = (row0 + t) * Q_ + q;
        idxi[item] = (int)k1;
        idxf[item] = (float)k1;
        if (fb) {
            resc[item] = 0xFFFFFFFFFFFFFFFFull;
            int p = atomicAdd(cntF, 1);
            listF[p] = item;
        } else if (ns > 0) {
            int p = atomicAdd(cntS, 1);
            int* e8 = srl + (size_t)p * 8;
            e8[0] = item; e8[1] = ns + 1; e8[2] = (int)k1;
            for (int i = 0; i < ns; i++)
                e8[3 + i] = (int)((candpack >> (12 * i)) & 0xFFFu);
        }
    }
}

// ---------------- exact fp32 rescue: shortlist blocks (<=6 cand) + full-scan fallback ----
__global__ void k_rescue(const float* __restrict__ xn, const float* __restrict__ cb,
                         const float* __restrict__ c2h, const int* __restrict__ listF,
                         const int* __restrict__ cntF, const int* __restrict__ srl,
                         const int* __restrict__ cntS,
                         unsigned long long* __restrict__ resc,
                         int* __restrict__ idxi, float* __restrict__ idxf) {
    __shared__ float xq[dd_];
    __shared__ unsigned long long kshare[8];
    const int t = threadIdx.x;
    if (blockIdx.x < 2048) {
        // ---- full-scan fallback: 8 blocks/item x 512 codewords ----
        const int n = *cntF;
        const int seg = blockIdx.x & 7;
        for (int ii = blockIdx.x >> 3; ii < n; ii += 256) {
            __syncthreads();
            int item = listF[ii];
            int rg = item >> 3, q = item & 7;
            if (t < dd_) xq[t] = xn[(size_t)rg * D_ + q * dd_ + t];
            __syncthreads();
            unsigned long long best = 0xFFFFFFFFFFFFFFFFull;
            #pragma unroll
            for (int i = 0; i < 2; i++) {
                int k = seg * 512 + i * 256 + t;
                const float* cp = cb + ((size_t)q * K_ + k) * dd_;
                float dot = 0.0f;
                #pragma unroll 8
                for (int d = 0; d < dd_; d += 4) {
                    f32x4 cv = *(const f32x4*)(cp + d);
                    dot = fmaf(cv.x, xq[d],     dot);
                    dot = fmaf(cv.y, xq[d + 1], dot);
                    dot = fmaf(cv.z, xq[d + 2], dot);
                    dot = fmaf(cv.w, xq[d + 3], dot);
                }
                float s = c2h[q * K_ + k] - dot;   // d2/2 - x2/2 (monotone in d2)
                unsigned long long key = ((unsigned long long)fflip(s) << 32) | (unsigned)k;
                best = best < key ? best : key;
            }
            #pragma unroll
            for (int o = 32; o > 0; o >>= 1) {
                unsigned long long other = shfl_xor_u64(best, o);
                best = best < other ? best : other;
            }
            if ((t & 63) == 0) kshare[t >> 6] = best;
            __syncthreads();
            if (t == 0) {
                unsigned long long b = kshare[0];
                b = b < kshare[1] ? b : kshare[1];
                b = b < kshare[2] ? b : kshare[2];
                b = b < kshare[3] ? b : kshare[3];
                atomicMin(&resc[item], b);
            }
        }
    } else {
        // ---- shortlist: 1 block/item, candidate per 32-lane group ----
        const int n = *cntS;
        for (int ii = (int)blockIdx.x - 2048; ii < n; ii += 2048) {
            __syncthreads();
            const int* e = srl + (size_t)ii * 8;
            int item = e[0], nc = e[1];
            int rg = item >> 3, q = item & 7;
            if (t < dd_) xq[t] = xn[(size_t)rg * D_ + q * dd_ + t];
            __syncthreads();
            int g = t >> 5, l = t & 31;
            unsigned long long key = 0xFFFFFFFFFFFFFFFFull;
            if (g < nc) {
                int k = e[2 + g];
                const float* cp = cb + ((size_t)q * K_ + k) * dd_ + l * 4;
                f32x4 cv = *(const f32x4*)cp;
                float dot = cv.x * xq[l * 4]     + cv.y * xq[l * 4 + 1]
                          + cv.z * xq[l * 4 + 2] + cv.w * xq[l * 4 + 3];
                dot += __shfl_xor(dot, 16, 64);
                dot += __shfl_xor(dot, 8, 64);
                dot += __shfl_xor(dot, 4, 64);
                dot += __shfl_xor(dot, 2, 64);
                dot += __shfl_xor(dot, 1, 64);
                float s = c2h[q * K_ + k] - dot;
                key = ((unsigned long long)fflip(s) << 32) | (unsigned)k;
            }
            if (l == 0) kshare[g] = key;
            __syncthreads();
            if (t == 0) {
                unsigned long long b = kshare[0];
                #pragma unroll
                for (int gg = 1; gg < 8; gg++) b = b < kshare[gg] ? b : kshare[gg];
                int k = (int)(unsigned)(b & 0xFFFFFFFFull);
                idxi[item] = k;
                idxf[item] = (float)k;
            }
        }
    }
}

// ---------------- decode full-scan winners into idxi/idxf ----------------
__global__ void k_fin(const int* __restrict__ listF, const int* __restrict__ cntF,
                      const unsigned long long* __restrict__ resc,
                      int* __restrict__ idxi, float* __restrict__ idxf) {
    const int n = *cntF;
    for (int i = blockIdx.x * blockDim.x + threadIdx.x; i < n; i += gridDim.x * blockDim.x) {
        int item = listF[i];
        int k = (int)(unsigned)(resc[item] & 0xFFFFFFFFull);
        idxi[item] = k;
        idxf[item] = (float)k;
    }
}

// ---------------- gather + output rmsnorm ----------------
__global__ void k_out(const float* __restrict__ cb, const int* __restrict__ idx_i,
                      const float* __restrict__ w, float* __restrict__ out) {
    int row = blockIdx.x;
    int t   = threadIdx.x;
    __shared__ int   sidx[Q_];
    __shared__ float acc[4];
    if (t < Q_) sidx[t] = idx_i[row * Q_ + t];
    __syncthreads();
    int col = t * 4;
    int q   = col >> 7;
    int dc  = col & 127;
    const float4 v = *(const float4*)(cb + ((size_t)q * K_ + sidx[q]) * dd_ + dc);
    float ss = v.x * v.x + v.y * v.y + v.z * v.z + v.w * v.w;
    #pragma unroll
    for (int o = 32; o > 0; o >>= 1) ss += __shfl_xor(ss, o, 64);
    if ((t & 63) == 0) acc[t >> 6] = ss;
    __syncthreads();
    float tot = (acc[0] + acc[1]) + (acc[2] + acc[3]);
    float sc  = 1.0f / sqrtf(tot * (1.0f / D_) + 1e-5f);
    const float4 wv = *(const float4*)(w + col);
    float4 o;
    o.x = v.x * sc * wv.x; o.y = v.y * sc * wv.y;
    o.z = v.z * sc * wv.z; o.w = v.w * sc * wv.w;
    *(float4*)(out + (size_t)row * D_ + col) = o;
}

extern "C" void kernel_launch(void* const* d_in, const int* in_sizes, int n_in,
                              void* d_out, int out_size, void* d_ws, size_t ws_size,
                              hipStream_t stream) {
    const float* x     = (const float*)d_in[0];
    const float* cb    = (const float*)d_in[1];
    const float* w_in  = (const float*)d_in[2];
    const float* w_out = (const float*)d_in[3];

    float* out  = (float*)d_out;                  // xn lives here between k_prep and k_out
    float* idxf = out + (size_t)ROWS * D_;

    // ws: panels 8MB | c2h 128KB | x2h 256KB | resc 512KB | idxi 256KB | listF 256KB
    //   | srl 2MB | cntF,cntS
    unsigned short* panels = (unsigned short*)d_ws;
    float* c2h  = (float*)((char*)d_ws + (8u << 20));
    float* x2h  = c2h + Q_ * K_;
    unsigned long long* resc = (unsigned long long*)(x2h + (size_t)ROWS * Q_);
    int*   idxi = (int*)(resc + (size_t)ROWS * Q_);
    int*   listF = idxi + ROWS * Q_;
    int*   srl  = listF + ROWS * Q_;
    int*   cntF = srl + (size_t)ROWS * Q_ * 8;
    int*   cntS = cntF + 1;

    k_prep  <<<dim3(NCHUNK * Q_ + ROWS), 256, 0, stream>>>(cb, x, w_in, out, panels, c2h, x2h, cntF, cntS);
    k_dist  <<<dim3(ROWS / 64, Q_),      256, 0, stream>>>(out, panels, c2h, x2h, idxi, idxf, listF, cntF, srl, cntS, resc);
    k_rescue<<<dim3(4096),               256, 0, stream>>>(out, cb, c2h, listF, cntF, srl, cntS, resc, idxi, idxf);
    k_fin   <<<dim3(64),                 256, 0, stream>>>(listF, cntF, resc, idxi, idxf);
    k_out   <<<dim3(ROWS),               256, 0, stream>>>(cb, idxi, w_out, out);
}

// Round 7
// 217.031 us; speedup vs baseline: 1.2608x; 1.1478x over previous
//
#include <hip/hip_runtime.h>
#include <math.h>
#include <float.h>

// VideoQuantizer: rmsnorm -> per-subvector argmin over 4096 codewords -> gather -> rmsnorm
// B=8 T=1024 D=1024 Q=8 K=4096 d=128
// v8: single-pass fp16 MFMA (al low-pass dropped -> MFMA work halved; error absorbed by
//     TAU 0.02->0.04). Sound capture at wide band: top-3 tracking per slot (m3, min3),
//     shortlist harvested from rm1 AND rm2, full-scan fallback only on m3-in-band or
//     overflow. k_fin folded into k_out via fb byte-map. v7's 64-row/4-blk-CU geometry.
#define Q_     8
#define K_     4096
#define dd_    128
#define D_     1024
#define ROWS   8192
#define NCHUNK 64
#define TAU    0.04f   // rescue band on d2/2 scale; 2E for fp16 A+B quant (~6 sigma)

typedef __attribute__((ext_vector_type(8))) _Float16 f16x8;
typedef __attribute__((ext_vector_type(4))) float f32x4;
typedef __attribute__((ext_vector_type(4))) unsigned int u32x4;

typedef const __attribute__((address_space(1))) unsigned int* gas_p;
typedef __attribute__((address_space(3))) unsigned int* las_p;

__device__ inline unsigned f2u(float x) { union { float f; unsigned u; } v; v.f = x; return v.u; }
__device__ inline float u2f(unsigned x) { union { unsigned u; float f; } v; v.u = x; return v.f; }
__device__ inline unsigned short f2h(float x) {
    union { _Float16 h; unsigned short u; } v; v.h = (_Float16)x; return v.u;
}
__device__ inline unsigned umin_(unsigned a, unsigned b) { return a < b ? a : b; }
__device__ inline unsigned umax_(unsigned a, unsigned b) { return a > b ? a : b; }
// order-preserving f32 -> u32 (total order; smaller float -> smaller uint)
__device__ inline unsigned fflip(float x) {
    unsigned u = f2u(x);
    return (u & 0x80000000u) ? ~u : (u | 0x80000000u);
}
__device__ inline unsigned long long shfl_xor_u64(unsigned long long v, int m) {
    unsigned lo = (unsigned)v, hi = (unsigned)(v >> 32);
    lo = __shfl_xor(lo, m, 64);
    hi = __shfl_xor(hi, m, 64);
    return ((unsigned long long)hi << 32) | lo;
}
// decode packed (tag|lane) -> codeword index; tag = (chunk<<1)|halfcol, e = lane index
__device__ inline unsigned dec_k(unsigned v, int e) {
    unsigned tg = v & 0x7Fu;
    return ((tg >> 1) << 6) | (((unsigned)e >> 4) << 5) | ((tg & 1u) << 4) | ((unsigned)e & 15u);
}

// ---------------- fused: panel build (negated fp16 plane) + c2/2 | input rmsnorm + x2/2 ----
// panels[q][c][n][slot][8 fp16] of NEGATED codewords; slot = j ^ (n&15)
__global__ void k_prep(const float* __restrict__ cb, const float* __restrict__ x,
                       const float* __restrict__ w, float* __restrict__ xn,
                       unsigned short* __restrict__ panels, float* __restrict__ c2h,
                       float* __restrict__ x2h, int* __restrict__ cntF, int* __restrict__ cntS) {
    const int bid = blockIdx.x, t = threadIdx.x;
    if (bid == 0 && t == 0) { *cntF = 0; *cntS = 0; }
    if (bid < NCHUNK * Q_) {
        // ---- panel prep ----
        int c = bid & 63, q = bid >> 6;
        const float* src = cb + ((size_t)q * K_ + c * 64) * dd_;
        unsigned short* dst = panels + (size_t)(q * NCHUNK + c) * 8192;
        #pragma unroll
        for (int i = 0; i < 4; i++) {
            int sid = i * 256 + t;
            int n = sid >> 4, j = sid & 15;
            const float* sp = src + n * dd_ + j * 8;
            f32x4 v0 = *(const f32x4*)sp;
            f32x4 v1 = *(const f32x4*)(sp + 4);
            float xs[8] = {v0.x, v0.y, v0.z, v0.w, v1.x, v1.y, v1.z, v1.w};
            unsigned short hb[8];
            float ss = 0.0f;
            #pragma unroll
            for (int e = 0; e < 8; e++) {
                float xv = -xs[e];                     // NEGATED codeword
                ss = fmaf(xv, xv, ss);
                hb[e] = f2h(xv);                       // single RTN fp16 plane
            }
            int slot = j ^ (n & 15);
            u32x4 H;
            H.x = (unsigned)hb[0] | ((unsigned)hb[1] << 16);
            H.y = (unsigned)hb[2] | ((unsigned)hb[3] << 16);
            H.z = (unsigned)hb[4] | ((unsigned)hb[5] << 16);
            H.w = (unsigned)hb[6] | ((unsigned)hb[7] << 16);
            *(u32x4*)&dst[(n * 16 + slot) * 8] = H;
            ss += __shfl_xor(ss, 1, 64);
            ss += __shfl_xor(ss, 2, 64);
            ss += __shfl_xor(ss, 4, 64);
            ss += __shfl_xor(ss, 8, 64);
            if (j == 0) c2h[q * K_ + c * 64 + n] = 0.5f * ss;   // exact f32 c2/2
        }
    } else {
        // ---- input rmsnorm + sub-vector x2/2 ----
        int row = bid - NCHUNK * Q_;
        const float4 v = *(const float4*)(x + (size_t)row * D_ + t * 4);
        float ss = v.x * v.x + v.y * v.y + v.z * v.z + v.w * v.w;
        #pragma unroll
        for (int o = 32; o > 0; o >>= 1) ss += __shfl_xor(ss, o, 64);
        __shared__ float acc[4];
        if ((t & 63) == 0) acc[t >> 6] = ss;
        __syncthreads();
        float tot = (acc[0] + acc[1]) + (acc[2] + acc[3]);
        float sc  = 1.0f / sqrtf(tot * (1.0f / D_) + 1e-5f);
        const float4 wv = *(const float4*)(w + t * 4);
        float4 o;
        o.x = v.x * sc * wv.x; o.y = v.y * sc * wv.y;
        o.z = v.z * sc * wv.z; o.w = v.w * sc * wv.w;
        *(float4*)(xn + (size_t)row * D_ + t * 4) = o;
        float so = o.x * o.x + o.y * o.y + o.z * o.z + o.w * o.w;
        so += __shfl_xor(so, 1, 64);
        so += __shfl_xor(so, 2, 64);
        so += __shfl_xor(so, 4, 64);
        so += __shfl_xor(so, 8, 64);
        so += __shfl_xor(so, 16, 64);
        if ((t & 31) == 0) x2h[row * Q_ + (t >> 5)] = 0.5f * so;
    }
}

// stage chunk CN's 16KB panel into its alternating 16KB LDS buffer
#define STAGE(CN) do {                                                                   \
    const char* src_ = (const char*)(panels + panq + (size_t)(CN) * 8192);               \
    char* stg_ = smem + ((CN) & 1) * 16384;                                              \
    _Pragma("unroll")                                                                    \
    for (int i_ = 0; i_ < 4; i_++) {                                                     \
        int boff_ = i_ * 4096 + t * 16;                                                  \
        __builtin_amdgcn_global_load_lds((gas_p)(src_ + boff_), (las_p)(stg_ + boff_),   \
                                         16, 0, 0);                                      \
    }                                                                                    \
} while (0)

// ---------------- single-pass fp16 MFMA distance (64-row blocks) + packed-u32 top-3 -------
// x,B both RTN fp16 (negated B). acc init = x2/2 + c2/2 -> acc_final ~ d2/2 (err<=TAU/2);
// pack (score&~0x7F)|tag, u32 top-3 per slot. Tail routing: shortlist from rm1+rm2,
// full-scan fallback only when a lane's 3rd (rm3) is in band or >5 rivals.
__launch_bounds__(256, 4)
__global__ void k_dist(const float* __restrict__ xn, const unsigned short* __restrict__ panels,
                       const float* __restrict__ c2h, const float* __restrict__ x2h,
                       int* __restrict__ idxi, float* __restrict__ idxf,
                       int* __restrict__ listF, int* __restrict__ cntF,
                       int* __restrict__ srl, int* __restrict__ cntS,
                       unsigned long long* __restrict__ resc,
                       unsigned char* __restrict__ fbm) {
    __shared__ char smem[32768];   // 2 x 16KB staging; reduce scratch (25344B) overlaid

    const int t    = threadIdx.x;
    const int lane = t & 63, wave = t >> 6;
    const int wm = wave >> 1, wn = wave & 1;
    const int col = lane & 15, quad = lane >> 4;
    const int q = blockIdx.y;
    const int row0 = blockIdx.x * 64;

    // A fragments: single RTN fp16, 2 mt per wave
    f16x8 ah[2][4];
    #pragma unroll
    for (int mt = 0; mt < 2; mt++) {
        #pragma unroll
        for (int kt = 0; kt < 4; kt++) {
            const float* ap = xn + (size_t)(row0 + wm * 32 + mt * 16 + col) * D_
                              + q * dd_ + kt * 32 + quad * 8;
            f32x4 v0 = *(const f32x4*)ap;
            f32x4 v1 = *(const f32x4*)(ap + 4);
            #pragma unroll
            for (int e = 0; e < 8; e++) {
                float xv = (e < 4) ? v0[e] : v1[e - 4];
                ah[mt][kt][e] = (_Float16)xv;
            }
        }
    }

    // per-slot row halves of ||x_q||^2
    f32x4 x2v[2];
    #pragma unroll
    for (int mt = 0; mt < 2; mt++)
        #pragma unroll
        for (int r = 0; r < 4; r++)
            x2v[mt][r] = x2h[(size_t)(row0 + wm * 32 + mt * 16 + quad * 4 + r) * Q_ + q];

    unsigned m1[8], m2[8], m3[8];
    #pragma unroll
    for (int i = 0; i < 8; i++) { m1[i] = 0xFFFFFFFFu; m2[i] = 0xFFFFFFFFu; m3[i] = 0xFFFFFFFFu; }

    const size_t panq = (size_t)q * NCHUNK * 8192;
    const float* c2hq = c2h + q * K_;

    STAGE(0);
    float ch0 = c2hq[wn * 32 + col];
    float ch1 = c2hq[wn * 32 + col + 16];

    for (int c = 0; c < NCHUNK; c++) {
        __syncthreads();
        if (c + 1 < NCHUNK) STAGE(c + 1);
        float ch0n = 0.0f, ch1n = 0.0f;
        if (c + 1 < NCHUNK) {
            ch0n = c2hq[(c + 1) * 64 + wn * 32 + col];
            ch1n = c2hq[(c + 1) * 64 + wn * 32 + col + 16];
        }
        const char* cbuf = smem + (c & 1) * 16384;

        f32x4 acc[2][2];
        #pragma unroll
        for (int mt = 0; mt < 2; mt++) {
            acc[mt][0] = x2v[mt] + ch0;   // d2/2 accumulator init
            acc[mt][1] = x2v[mt] + ch1;
        }

        #pragma unroll
        for (int kt = 0; kt < 4; kt++) {
            const int sw = ((quad + kt * 4) ^ col) * 16;
            const int a0 = (wn * 32 + col) * 256 + sw;        // codeword rows 0..15 of half 0
            const int a1 = a0 + 4096;                         // +16 rows (half 1)
            f16x8 b0 = *(const f16x8*)(cbuf + a0);
            f16x8 b1 = *(const f16x8*)(cbuf + a1);
            #pragma unroll
            for (int mt = 0; mt < 2; mt++) {
                acc[mt][0] = __builtin_amdgcn_mfma_f32_16x16x32_f16(ah[mt][kt], b0, acc[mt][0], 0, 0, 0);
                acc[mt][1] = __builtin_amdgcn_mfma_f32_16x16x32_f16(ah[mt][kt], b1, acc[mt][1], 0, 0, 0);
            }
        }

        const unsigned tg0 = (unsigned)(c << 1), tg1 = tg0 | 1u;
        #pragma unroll
        for (int mt = 0; mt < 2; mt++) {
            #pragma unroll
            for (int r = 0; r < 4; r++) {
                const int sl = mt * 4 + r;
                unsigned p0 = (f2u(acc[mt][0][r]) & 0xFFFFFF80u) | tg0;
                unsigned p1 = (f2u(acc[mt][1][r]) & 0xFFFFFF80u) | tg1;
                unsigned pmin = umin_(p0, p1), pmax = umax_(p0, p1);
                // merge sorted {m1,m2,m3} with {pmin,pmax} -> new top-3
                unsigned a1m = umax_(m1[sl], pmin);
                unsigned a2m = umin_(m2[sl], pmax);
                unsigned a4m = umax_(m2[sl], pmax);
                m1[sl] = umin_(m1[sl], pmin);
                m2[sl] = umin_(a1m, a2m);
                unsigned a3m = umax_(a1m, a2m);
                m3[sl] = umin_(umin_(a3m, a4m), m3[sl]);   // min3
            }
        }
        ch0 = ch0n; ch1 = ch1n;
    }

    // cross-lane merge per row (u32 domain; stride 33): min + shortlist + fallback detect
    __syncthreads();
    unsigned* rm1 = (unsigned*)smem;             // [64][33]
    unsigned* rm2 = (unsigned*)(smem + 8448);
    unsigned* rm3 = (unsigned*)(smem + 16896);
    #pragma unroll
    for (int mt = 0; mt < 2; mt++) {
        #pragma unroll
        for (int r = 0; r < 4; r++) {
            int sl = mt * 4 + r;
            int row_l = wm * 32 + mt * 16 + quad * 4 + r;
            int e = wn * 16 + col;
            rm1[row_l * 33 + e] = m1[sl];
            rm2[row_l * 33 + e] = m2[sl];
            rm3[row_l * 33 + e] = m3[sl];
        }
    }
    __syncthreads();
    if (t < 64) {
        unsigned b1 = 0xFFFFFFFFu;
        int be = 0;
        for (int e = 0; e < 32; e++) {
            unsigned v1 = rm1[t * 33 + e];
            if (v1 < b1) { b1 = v1; be = e; }
        }
        float thr = u2f(b1 & 0xFFFFFF80u) + TAU;
        int ns = 0, fb = 0;
        unsigned long long candpack = 0;
        for (int e = 0; e < 32; e++) {
            unsigned v1 = rm1[t * 33 + e];
            unsigned v2 = rm2[t * 33 + e];
            unsigned v3 = rm3[t * 33 + e];
            if (u2f(v3 & 0xFFFFFF80u) < thr) fb = 1;   // hidden 3rd-in-lane possible
            if (e != be && u2f(v1 & 0xFFFFFF80u) < thr) {
                if (ns < 5) candpack |= (unsigned long long)dec_k(v1, e) << (12 * ns);
                ns++;
            }
            if (u2f(v2 & 0xFFFFFF80u) < thr) {         // lane's 2nd (incl. winner's lane)
                if (ns < 5) candpack |= (unsigned long long)dec_k(v2, e) << (12 * ns);
                ns++;
            }
        }
        if (ns > 5) fb = 1;
        unsigned k1 = dec_k(b1, be);
        int item = (row0 + t) * Q_ + q;
        idxi[item] = (int)k1;
        idxf[item] = (float)k1;
        fbm[item] = (unsigned char)fb;
        if (fb) {
            resc[item] = 0xFFFFFFFFFFFFFFFFull;
            int p = atomicAdd(cntF, 1);
            listF[p] = item;
        } else if (ns > 0) {
            int p = atomicAdd(cntS, 1);
            int* e8 = srl + (size_t)p * 8;
            e8[0] = item; e8[1] = ns + 1; e8[2] = (int)k1;
            for (int i = 0; i < ns; i++)
                e8[3 + i] = (int)((candpack >> (12 * i)) & 0xFFFu);
        }
    }
}

// ---------------- exact fp32 rescue: shortlist blocks (<=6 cand) + full-scan fallback ----
__global__ void k_rescue(const float* __restrict__ xn, const float* __restrict__ cb,
                         const float* __restrict__ c2h, const int* __restrict__ listF,
                         const int* __restrict__ cntF, const int* __restrict__ srl,
                         const int* __restrict__ cntS,
                         unsigned long long* __restrict__ resc,
                         int* __restrict__ idxi, float* __restrict__ idxf) {
    __shared__ float xq[dd_];
    __shared__ unsigned long long kshare[8];
    const int t = threadIdx.x;
    if (blockIdx.x < 2048) {
        // ---- full-scan fallback: 8 blocks/item x 512 codewords ----
        const int n = *cntF;
        const int seg = blockIdx.x & 7;
        for (int ii = blockIdx.x >> 3; ii < n; ii += 256) {
            __syncthreads();
            int item = listF[ii];
            int rg = item >> 3, q = item & 7;
            if (t < dd_) xq[t] = xn[(size_t)rg * D_ + q * dd_ + t];
            __syncthreads();
            unsigned long long best = 0xFFFFFFFFFFFFFFFFull;
            #pragma unroll
            for (int i = 0; i < 2; i++) {
                int k = seg * 512 + i * 256 + t;
                const float* cp = cb + ((size_t)q * K_ + k) * dd_;
                float dot = 0.0f;
                #pragma unroll 8
                for (int d = 0; d < dd_; d += 4) {
                    f32x4 cv = *(const f32x4*)(cp + d);
                    dot = fmaf(cv.x, xq[d],     dot);
                    dot = fmaf(cv.y, xq[d + 1], dot);
                    dot = fmaf(cv.z, xq[d + 2], dot);
                    dot = fmaf(cv.w, xq[d + 3], dot);
                }
                float s = c2h[q * K_ + k] - dot;   // d2/2 - x2/2 (monotone in d2)
                unsigned long long key = ((unsigned long long)fflip(s) << 32) | (unsigned)k;
                best = best < key ? best : key;
            }
            #pragma unroll
            for (int o = 32; o > 0; o >>= 1) {
                unsigned long long other = shfl_xor_u64(best, o);
                best = best < other ? best : other;
            }
            if ((t & 63) == 0) kshare[t >> 6] = best;
            __syncthreads();
            if (t == 0) {
                unsigned long long b = kshare[0];
                b = b < kshare[1] ? b : kshare[1];
                b = b < kshare[2] ? b : kshare[2];
                b = b < kshare[3] ? b : kshare[3];
                atomicMin(&resc[item], b);
            }
        }
    } else {
        // ---- shortlist: 1 block/item, candidate per 32-lane group ----
        const int n = *cntS;
        for (int ii = (int)blockIdx.x - 2048; ii < n; ii += 2048) {
            __syncthreads();
            const int* e = srl + (size_t)ii * 8;
            int item = e[0], nc = e[1];
            int rg = item >> 3, q = item & 7;
            if (t < dd_) xq[t] = xn[(size_t)rg * D_ + q * dd_ + t];
            __syncthreads();
            int g = t >> 5, l = t & 31;
            unsigned long long key = 0xFFFFFFFFFFFFFFFFull;
            if (g < nc) {
                int k = e[2 + g];
                const float* cp = cb + ((size_t)q * K_ + k) * dd_ + l * 4;
                f32x4 cv = *(const f32x4*)cp;
                float dot = cv.x * xq[l * 4]     + cv.y * xq[l * 4 + 1]
                          + cv.z * xq[l * 4 + 2] + cv.w * xq[l * 4 + 3];
                dot += __shfl_xor(dot, 16, 64);
                dot += __shfl_xor(dot, 8, 64);
                dot += __shfl_xor(dot, 4, 64);
                dot += __shfl_xor(dot, 2, 64);
                dot += __shfl_xor(dot, 1, 64);
                float s = c2h[q * K_ + k] - dot;
                key = ((unsigned long long)fflip(s) << 32) | (unsigned)k;
            }
            if (l == 0) kshare[g] = key;
            __syncthreads();
            if (t == 0) {
                unsigned long long b = kshare[0];
                #pragma unroll
                for (int gg = 1; gg < 8; gg++) b = b < kshare[gg] ? b : kshare[gg];
                int k = (int)(unsigned)(b & 0xFFFFFFFFull);
                idxi[item] = k;
                idxf[item] = (float)k;
            }
        }
    }
}

// ---------------- gather + output rmsnorm (+ fold-in of fallback decode) ----------------
__global__ void k_out(const float* __restrict__ cb, const int* __restrict__ idx_i,
                      const unsigned long long* __restrict__ resc,
                      const unsigned char* __restrict__ fbm,
                      const float* __restrict__ w, float* __restrict__ out,
                      float* __restrict__ idxf) {
    int row = blockIdx.x;
    int t   = threadIdx.x;
    __shared__ int   sidx[Q_];
    __shared__ float acc[4];
    if (t < Q_) {
        int item = row * Q_ + t;
        int k = idx_i[item];
        if (fbm[item]) {                       // fallback winner decoded here (k_fin folded)
            k = (int)(unsigned)(resc[item] & 0xFFFFFFFFull);
            idxf[item] = (float)k;
        }
        sidx[t] = k;
    }
    __syncthreads();
    int col = t * 4;
    int q   = col >> 7;
    int dc  = col & 127;
    const float4 v = *(const float4*)(cb + ((size_t)q * K_ + sidx[q]) * dd_ + dc);
    float ss = v.x * v.x + v.y * v.y + v.z * v.z + v.w * v.w;
    #pragma unroll
    for (int o = 32; o > 0; o >>= 1) ss += __shfl_xor(ss, o, 64);
    if ((t & 63) == 0) acc[t >> 6] = ss;
    __syncthreads();
    float tot = (acc[0] + acc[1]) + (acc[2] + acc[3]);
    float sc  = 1.0f / sqrtf(tot * (1.0f / D_) + 1e-5f);
    const float4 wv = *(const float4*)(w + col);
    float4 o;
    o.x = v.x * sc * wv.x; o.y = v.y * sc * wv.y;
    o.z = v.z * sc * wv.z; o.w = v.w * sc * wv.w;
    *(float4*)(out + (size_t)row * D_ + col) = o;
}

extern "C" void kernel_launch(void* const* d_in, const int* in_sizes, int n_in,
                              void* d_out, int out_size, void* d_ws, size_t ws_size,
                              hipStream_t stream) {
    const float* x     = (const float*)d_in[0];
    const float* cb    = (const float*)d_in[1];
    const float* w_in  = (const float*)d_in[2];
    const float* w_out = (const float*)d_in[3];

    float* out  = (float*)d_out;                  // xn lives here between k_prep and k_out
    float* idxf = out + (size_t)ROWS * D_;

    // ws: panels 8MB | c2h 128KB | x2h 256KB | resc 512KB | idxi 256KB | listF 256KB
    //   | srl 2MB | fbm 64KB | cntF,cntS
    unsigned short* panels = (unsigned short*)d_ws;
    float* c2h  = (float*)((char*)d_ws + (8u << 20));
    float* x2h  = c2h + Q_ * K_;
    unsigned long long* resc = (unsigned long long*)(x2h + (size_t)ROWS * Q_);
    int*   idxi = (int*)(resc + (size_t)ROWS * Q_);
    int*   listF = idxi + ROWS * Q_;
    int*   srl  = listF + ROWS * Q_;
    unsigned char* fbm = (unsigned char*)(srl + (size_t)ROWS * Q_ * 8);
    int*   cntF = (int*)(fbm + ROWS * Q_);
    int*   cntS = cntF + 1;

    k_prep  <<<dim3(NCHUNK * Q_ + ROWS), 256, 0, stream>>>(cb, x, w_in, out, panels, c2h, x2h, cntF, cntS);
    k_dist  <<<dim3(ROWS / 64, Q_),      256, 0, stream>>>(out, panels, c2h, x2h, idxi, idxf, listF, cntF, srl, cntS, resc, fbm);
    k_rescue<<<dim3(4096),               256, 0, stream>>>(out, cb, c2h, listF, cntF, srl, cntS, resc, idxi, idxf);
    k_out   <<<dim3(ROWS),               256, 0, stream>>>(cb, idxi, resc, fbm, w_out, out, idxf);
}